// Round 2
// baseline (561.754 us; speedup 1.0000x reference)
//
#include <hip/hip_runtime.h>
#include <stdint.h>

#define MM 8192   // B*S = 4*2048
#define NN 4096
#define KK 4096
#define BM 128
#define BN 128
#define BK 32

typedef __bf16 bf16x8 __attribute__((ext_vector_type(8)));
typedef float  f32x4  __attribute__((ext_vector_type(4)));

__device__ __forceinline__ unsigned short f2bf(float f) {
    union { float f; uint32_t u; } v; v.f = f;
    uint32_t r = v.u + 0x7fffu + ((v.u >> 16) & 1u);   // RTNE
    return (unsigned short)(r >> 16);
}

// pack two fp32 -> two bf16 (round-half-up; 1 add/elem + 1 v_perm per pair)
__device__ __forceinline__ uint32_t pk2bf(float lo, float hi) {
    union { float f; uint32_t u; } a, b; a.f = lo; b.f = hi;
    return __builtin_amdgcn_perm(b.u + 0x8000u, a.u + 0x8000u, 0x07060302u);
}

__device__ __forceinline__ void gld16(const void* g, void* l) {
    __builtin_amdgcn_global_load_lds(
        (const __attribute__((address_space(1))) void*)g,
        (__attribute__((address_space(3))) void*)l, 16, 0, 0);
}

// ---- x (M x K fp32) -> bf16, same layout (fast path only) ----
__global__ void cvt_x(const float* __restrict__ x, unsigned short* __restrict__ xb) {
    size_t i = ((size_t)blockIdx.x * blockDim.x + threadIdx.x) * 8;
    float4 a = *(const float4*)(x + i);
    float4 b = *(const float4*)(x + i + 4);
    unsigned short h[8];
    h[0] = f2bf(a.x); h[1] = f2bf(a.y); h[2] = f2bf(a.z); h[3] = f2bf(a.w);
    h[4] = f2bf(b.x); h[5] = f2bf(b.y); h[6] = f2bf(b.z); h[7] = f2bf(b.w);
    *(uint4*)(xb + i) = *(uint4*)h;
}

// ---- W (K x N fp32) -> Wt (N x K bf16), LDS-tiled transpose ----
__global__ void cvt_wt(const float* __restrict__ W, unsigned short* __restrict__ wt) {
    __shared__ float tile[32][33];
    int n0 = blockIdx.x * 32, k0 = blockIdx.y * 32;
    int tx = threadIdx.x, ty = threadIdx.y;   // (32, 8)
    #pragma unroll
    for (int r = 0; r < 32; r += 8)
        tile[ty + r][tx] = W[(size_t)(k0 + ty + r) * NN + n0 + tx];
    __syncthreads();
    #pragma unroll
    for (int r = 0; r < 32; r += 8)
        wt[(size_t)(n0 + ty + r) * KK + k0 + tx] = f2bf(tile[tx][ty + r]);
}

// ---- C = A(MxK) * Wt^T(KxN) + bias, bf16 MFMA, fp32 out ----
// AFP32: A source is fp32 (x itself); convert during staging via VGPR path.
template<bool AFP32>
__global__ __launch_bounds__(256) void gemm_bt(
    const void* __restrict__ Aptr,          // bf16 (M x K) or fp32 (M x K)
    const unsigned short* __restrict__ Bt,  // N x K bf16
    const float* __restrict__ bias,
    float* __restrict__ C)                  // M x N fp32
{
    __shared__ unsigned short As[BM * BK];
    __shared__ unsigned short Bs[BN * BK];

    const int tid  = threadIdx.x;
    const int lane = tid & 63;
    const int wave = tid >> 6;              // 0..3
    const int wm   = (wave >> 1) * 64;
    const int wn   = (wave & 1)  * 64;

    const int bn = blockIdx.x * BN;
    const int bm = blockIdx.y * BM;

    // staging: 2 chunks of 8 elems per thread per tile (4096 elems / 256 thr)
    const int c0 = tid, c1 = tid + 256;
    const int r0 = c0 >> 2, k0o = (c0 & 3) * 8;
    const int r1 = c1 >> 2, k1o = (c1 & 3) * 8;

    const unsigned short* b0 = Bt + (size_t)(bn + r0) * KK + k0o;
    const unsigned short* b1 = Bt + (size_t)(bn + r1) * KK + k1o;
    unsigned short* asl0 = &As[c0 * 8]; unsigned short* asl1 = &As[c1 * 8];
    unsigned short* bsl0 = &Bs[c0 * 8]; unsigned short* bsl1 = &Bs[c1 * 8];

    const unsigned short* a0h = nullptr; const unsigned short* a1h = nullptr;
    const float* a0f = nullptr; const float* a1f = nullptr;
    if constexpr (AFP32) {
        a0f = (const float*)Aptr + (size_t)(bm + r0) * KK + k0o;
        a1f = (const float*)Aptr + (size_t)(bm + r1) * KK + k1o;
    } else {
        a0h = (const unsigned short*)Aptr + (size_t)(bm + r0) * KK + k0o;
        a1h = (const unsigned short*)Aptr + (size_t)(bm + r1) * KK + k1o;
    }

    const int fm = lane & 15;               // m (A) / n (B) within 16-tile
    const int fk = (lane >> 4) * 8;         // k-offset of this lane's 8 elems

    f32x4 acc[4][4] = {};

    for (int kk = 0; kk < KK; kk += BK) {
        __syncthreads();                    // prior iter's LDS reads done
        if constexpr (AFP32) {
            float4 f00 = *(const float4*)(a0f + kk);
            float4 f01 = *(const float4*)(a0f + kk + 4);
            float4 f10 = *(const float4*)(a1f + kk);
            float4 f11 = *(const float4*)(a1f + kk + 4);
            gld16(b0 + kk, bsl0);
            gld16(b1 + kk, bsl1);
            uint4 p0, p1;
            p0.x = pk2bf(f00.x, f00.y); p0.y = pk2bf(f00.z, f00.w);
            p0.z = pk2bf(f01.x, f01.y); p0.w = pk2bf(f01.z, f01.w);
            p1.x = pk2bf(f10.x, f10.y); p1.y = pk2bf(f10.z, f10.w);
            p1.z = pk2bf(f11.x, f11.y); p1.w = pk2bf(f11.z, f11.w);
            *(uint4*)asl0 = p0;
            *(uint4*)asl1 = p1;
        } else {
            gld16(a0h + kk, asl0);
            gld16(a1h + kk, asl1);
            gld16(b0 + kk, bsl0);
            gld16(b1 + kk, bsl1);
        }
        __syncthreads();                    // staging drained before reads

        bf16x8 fa[4], fb[4];
        #pragma unroll
        for (int i = 0; i < 4; i++)
            fa[i] = *(bf16x8*)&As[(wm + i * 16 + fm) * BK + fk];
        #pragma unroll
        for (int j = 0; j < 4; j++)
            fb[j] = *(bf16x8*)&Bs[(wn + j * 16 + fm) * BK + fk];
        #pragma unroll
        for (int i = 0; i < 4; i++)
            #pragma unroll
            for (int j = 0; j < 4; j++)
                acc[i][j] = __builtin_amdgcn_mfma_f32_16x16x32_bf16(
                    fa[i], fb[j], acc[i][j], 0, 0, 0);
    }

    // epilogue: C/D layout col=lane&15, row=(lane>>4)*4+reg  [m89/m91 verified]
    const int row4 = (lane >> 4) * 4;
    float bv[4];
    #pragma unroll
    for (int j = 0; j < 4; j++) bv[j] = bias[bn + wn + j * 16 + fm];
    #pragma unroll
    for (int i = 0; i < 4; i++) {
        #pragma unroll
        for (int r = 0; r < 4; r++) {
            const int m = bm + wm + i * 16 + row4 + r;
            float* crow = C + (size_t)m * NN + bn + wn + fm;
            #pragma unroll
            for (int j = 0; j < 4; j++)
                crow[j * 16] = acc[i][j][r] + bv[j];
        }
    }
}

// ---- insurance fallback: fp32 vector GEMM, zero workspace ----
__global__ __launch_bounds__(256) void gemm_f32(
    const float* __restrict__ A, const float* __restrict__ W,
    const float* __restrict__ bias, float* __restrict__ C)
{
    __shared__ float As[16][68];
    __shared__ float Ws[16][68];
    const int tid = threadIdx.x;
    const int bm = blockIdx.y * 64, bn = blockIdx.x * 64;
    const int tx = tid & 15, ty = tid >> 4;
    const int am = tid >> 2, ak = (tid & 3) * 4;
    const int wk = tid >> 4, wn = (tid & 15) * 4;
    float acc[4][4] = {};
    for (int kk = 0; kk < KK; kk += 16) {
        float4 av = *(const float4*)(A + (size_t)(bm + am) * KK + kk + ak);
        float4 wv = *(const float4*)(W + (size_t)(kk + wk) * NN + bn + wn);
        __syncthreads();
        As[ak + 0][am] = av.x; As[ak + 1][am] = av.y;
        As[ak + 2][am] = av.z; As[ak + 3][am] = av.w;
        Ws[wk][wn] = wv.x; Ws[wk][wn + 1] = wv.y;
        Ws[wk][wn + 2] = wv.z; Ws[wk][wn + 3] = wv.w;
        __syncthreads();
        #pragma unroll
        for (int k = 0; k < 16; k++) {
            float a[4], b[4];
            #pragma unroll
            for (int i = 0; i < 4; i++) a[i] = As[k][ty * 4 + i];
            #pragma unroll
            for (int j = 0; j < 4; j++) b[j] = Ws[k][tx * 4 + j];
            #pragma unroll
            for (int i = 0; i < 4; i++)
                #pragma unroll
                for (int j = 0; j < 4; j++)
                    acc[i][j] += a[i] * b[j];
        }
    }
    #pragma unroll
    for (int i = 0; i < 4; i++)
        #pragma unroll
        for (int j = 0; j < 4; j++)
            C[(size_t)(bm + ty * 4 + i) * NN + bn + tx * 4 + j] =
                acc[i][j] + bias[bn + tx * 4 + j];
}

extern "C" void kernel_launch(void* const* d_in, const int* in_sizes, int n_in,
                              void* d_out, int out_size, void* d_ws, size_t ws_size,
                              hipStream_t stream) {
    const float* x    = (const float*)d_in[0];
    const float* W    = (const float*)d_in[1];
    const float* bias = (const float*)d_in[2];
    float* out = (float*)d_out;

    const size_t need_wt   = (size_t)NN * KK * 2;              // 32 MiB
    const size_t need_full = need_wt + (size_t)MM * KK * 2;    // 96 MiB

    if (ws_size >= need_full) {
        // fast path: both operands pre-converted to bf16 in ws
        unsigned short* wt = (unsigned short*)d_ws;
        unsigned short* xb = wt + (size_t)NN * KK;
        cvt_x<<<(size_t)MM * KK / (256 * 8), 256, 0, stream>>>(x, xb);
        cvt_wt<<<dim3(NN / 32, KK / 32), dim3(32, 8), 0, stream>>>(W, wt);
        gemm_bt<false><<<dim3(NN / BN, MM / BM), 256, 0, stream>>>(xb, wt, bias, out);
    } else if (ws_size >= need_wt) {
        // wt-only path: W transposed+cast in ws; x converted during staging
        unsigned short* wt = (unsigned short*)d_ws;
        cvt_wt<<<dim3(NN / 32, KK / 32), dim3(32, 8), 0, stream>>>(W, wt);
        gemm_bt<true><<<dim3(NN / BN, MM / BM), 256, 0, stream>>>(x, wt, bias, out);
    } else {
        // insurance: fp32 vector GEMM, no workspace
        gemm_f32<<<dim3(NN / 64, MM / 64), 256, 0, stream>>>(x, W, bias, out);
    }
}

// Round 3
// 550.825 us; speedup vs baseline: 1.0198x; 1.0198x over previous
//
#include <hip/hip_runtime.h>
#include <stdint.h>

#define MM 8192   // B*S = 4*2048
#define NN 4096
#define KK 4096
#define BM 128
#define BN 128
#define BK 32
#define WTBLKS 4096   // 64x64 transpose tiles: (4096/64)^2

typedef __bf16 bf16x8 __attribute__((ext_vector_type(8)));
typedef float  f32x4  __attribute__((ext_vector_type(4)));

__device__ __forceinline__ unsigned short f2bf(float f) {
    union { float f; uint32_t u; } v; v.f = f;
    uint32_t r = v.u + 0x7fffu + ((v.u >> 16) & 1u);   // RTNE
    return (unsigned short)(r >> 16);
}

// pack two fp32 -> two bf16 lanes (RTNE)
__device__ __forceinline__ uint32_t pk2(float lo, float hi) {
    return (uint32_t)f2bf(lo) | ((uint32_t)f2bf(hi) << 16);
}

__device__ __forceinline__ void gld16(const void* g, void* l) {
    __builtin_amdgcn_global_load_lds(
        (const __attribute__((address_space(1))) void*)g,
        (__attribute__((address_space(3))) void*)l, 16, 0, 0);
}

// ---- fused prep: blocks [0,WTBLKS) transpose+cast W -> Wt (N x K bf16);
//      blocks [WTBLKS, WTBLKS+xblks) cast x -> xb (M x K bf16).
//      Launch with grid = WTBLKS (wt only) or WTBLKS + MM*KK/2048 (both).
__global__ __launch_bounds__(256) void prep(
    const float* __restrict__ x, const float* __restrict__ W,
    unsigned short* __restrict__ xb, unsigned short* __restrict__ wt)
{
    __shared__ float t[64][65];   // t[n][k], pad 65 -> <=2-way bank aliasing
    const int b = blockIdx.x;
    const int tid = threadIdx.x;

    if (b < WTBLKS) {
        const int n0 = (b & 63) * 64;
        const int k0 = (b >> 6) * 64;
        // read phase: float4 rows of W (k-major), store transposed to LDS
        const int kr = tid >> 4;          // 0..15
        const int nf = (tid & 15) * 4;    // 0..60
        #pragma unroll
        for (int p = 0; p < 4; p++) {
            const int k = p * 16 + kr;
            float4 v = *(const float4*)(W + (size_t)(k0 + k) * NN + n0 + nf);
            t[nf + 0][k] = v.x; t[nf + 1][k] = v.y;
            t[nf + 2][k] = v.z; t[nf + 3][k] = v.w;
        }
        __syncthreads();
        // write phase: 8 bf16 per thread -> uint4; 8 threads cover 128B/row
        const int nr = tid >> 3;          // 0..31
        const int kc = (tid & 7) * 8;     // 0..56
        #pragma unroll
        for (int p = 0; p < 2; p++) {
            const int n = p * 32 + nr;
            uint32_t h[4];
            #pragma unroll
            for (int j = 0; j < 4; j++)
                h[j] = pk2(t[n][kc + 2 * j], t[n][kc + 2 * j + 1]);
            *(uint4*)(wt + (size_t)(n0 + n) * KK + k0 + kc) = *(uint4*)h;
        }
    } else {
        size_t i = ((size_t)(b - WTBLKS) * 256 + tid) * 8;
        float4 a = *(const float4*)(x + i);
        float4 c = *(const float4*)(x + i + 4);
        uint32_t h[4];
        h[0] = pk2(a.x, a.y); h[1] = pk2(a.z, a.w);
        h[2] = pk2(c.x, c.y); h[3] = pk2(c.z, c.w);
        *(uint4*)(xb + i) = *(uint4*)h;
    }
}

// ---- C = A(MxK) * Wt^T(KxN) + bias, bf16 MFMA, fp32 out ----
// AFP32: A source is fp32 (x itself); convert during staging via VGPR path.
template<bool AFP32>
__global__ __launch_bounds__(256) void gemm_bt(
    const void* __restrict__ Aptr,          // bf16 (M x K) or fp32 (M x K)
    const unsigned short* __restrict__ Bt,  // N x K bf16
    const float* __restrict__ bias,
    float* __restrict__ C)                  // M x N fp32
{
    __shared__ unsigned short As[BM * BK];
    __shared__ unsigned short Bs[BN * BK];

    const int tid  = threadIdx.x;
    const int lane = tid & 63;
    const int wave = tid >> 6;              // 0..3
    const int wm   = (wave >> 1) * 64;
    const int wn   = (wave & 1)  * 64;

    const int bn = blockIdx.x * BN;
    const int bm = blockIdx.y * BM;

    // staging: 2 chunks of 8 elems per thread per tile (4096 elems / 256 thr)
    const int c0 = tid, c1 = tid + 256;
    const int r0 = c0 >> 2, k0o = (c0 & 3) * 8;
    const int r1 = c1 >> 2, k1o = (c1 & 3) * 8;

    const unsigned short* b0 = Bt + (size_t)(bn + r0) * KK + k0o;
    const unsigned short* b1 = Bt + (size_t)(bn + r1) * KK + k1o;
    unsigned short* asl0 = &As[c0 * 8]; unsigned short* asl1 = &As[c1 * 8];
    unsigned short* bsl0 = &Bs[c0 * 8]; unsigned short* bsl1 = &Bs[c1 * 8];

    const unsigned short* a0h = nullptr; const unsigned short* a1h = nullptr;
    const float* a0f = nullptr; const float* a1f = nullptr;
    if constexpr (AFP32) {
        a0f = (const float*)Aptr + (size_t)(bm + r0) * KK + k0o;
        a1f = (const float*)Aptr + (size_t)(bm + r1) * KK + k1o;
    } else {
        a0h = (const unsigned short*)Aptr + (size_t)(bm + r0) * KK + k0o;
        a1h = (const unsigned short*)Aptr + (size_t)(bm + r1) * KK + k1o;
    }

    const int fm = lane & 15;               // m (A) / n (B) within 16-tile
    const int fk = (lane >> 4) * 8;         // k-offset of this lane's 8 elems

    f32x4 acc[4][4] = {};

    for (int kk = 0; kk < KK; kk += BK) {
        __syncthreads();                    // prior iter's LDS reads done
        if constexpr (AFP32) {
            float4 f00 = *(const float4*)(a0f + kk);
            float4 f01 = *(const float4*)(a0f + kk + 4);
            float4 f10 = *(const float4*)(a1f + kk);
            float4 f11 = *(const float4*)(a1f + kk + 4);
            gld16(b0 + kk, bsl0);
            gld16(b1 + kk, bsl1);
            uint4 p0, p1;
            p0.x = pk2(f00.x, f00.y); p0.y = pk2(f00.z, f00.w);
            p0.z = pk2(f01.x, f01.y); p0.w = pk2(f01.z, f01.w);
            p1.x = pk2(f10.x, f10.y); p1.y = pk2(f10.z, f10.w);
            p1.z = pk2(f11.x, f11.y); p1.w = pk2(f11.z, f11.w);
            *(uint4*)asl0 = p0;
            *(uint4*)asl1 = p1;
        } else {
            gld16(a0h + kk, asl0);
            gld16(a1h + kk, asl1);
            gld16(b0 + kk, bsl0);
            gld16(b1 + kk, bsl1);
        }
        __syncthreads();                    // staging drained before reads

        bf16x8 fa[4], fb[4];
        #pragma unroll
        for (int i = 0; i < 4; i++)
            fa[i] = *(bf16x8*)&As[(wm + i * 16 + fm) * BK + fk];
        #pragma unroll
        for (int j = 0; j < 4; j++)
            fb[j] = *(bf16x8*)&Bs[(wn + j * 16 + fm) * BK + fk];
        #pragma unroll
        for (int i = 0; i < 4; i++)
            #pragma unroll
            for (int j = 0; j < 4; j++)
                acc[i][j] = __builtin_amdgcn_mfma_f32_16x16x32_bf16(
                    fa[i], fb[j], acc[i][j], 0, 0, 0);
    }

    // epilogue: C/D layout col=lane&15, row=(lane>>4)*4+reg  [m89/m91 verified]
    const int row4 = (lane >> 4) * 4;
    float bv[4];
    #pragma unroll
    for (int j = 0; j < 4; j++) bv[j] = bias[bn + wn + j * 16 + fm];
    #pragma unroll
    for (int i = 0; i < 4; i++) {
        #pragma unroll
        for (int r = 0; r < 4; r++) {
            const int m = bm + wm + i * 16 + row4 + r;
            float* crow = C + (size_t)m * NN + bn + wn + fm;
            #pragma unroll
            for (int j = 0; j < 4; j++)
                crow[j * 16] = acc[i][j][r] + bv[j];
        }
    }
}

// ---- insurance fallback: fp32 vector GEMM, zero workspace ----
__global__ __launch_bounds__(256) void gemm_f32(
    const float* __restrict__ A, const float* __restrict__ W,
    const float* __restrict__ bias, float* __restrict__ C)
{
    __shared__ float As[16][68];
    __shared__ float Ws[16][68];
    const int tid = threadIdx.x;
    const int bm = blockIdx.y * 64, bn = blockIdx.x * 64;
    const int tx = tid & 15, ty = tid >> 4;
    const int am = tid >> 2, ak = (tid & 3) * 4;
    const int wk = tid >> 4, wn = (tid & 15) * 4;
    float acc[4][4] = {};
    for (int kk = 0; kk < KK; kk += 16) {
        float4 av = *(const float4*)(A + (size_t)(bm + am) * KK + kk + ak);
        float4 wv = *(const float4*)(W + (size_t)(kk + wk) * NN + bn + wn);
        __syncthreads();
        As[ak + 0][am] = av.x; As[ak + 1][am] = av.y;
        As[ak + 2][am] = av.z; As[ak + 3][am] = av.w;
        Ws[wk][wn] = wv.x; Ws[wk][wn + 1] = wv.y;
        Ws[wk][wn + 2] = wv.z; Ws[wk][wn + 3] = wv.w;
        __syncthreads();
        #pragma unroll
        for (int k = 0; k < 16; k++) {
            float a[4], b[4];
            #pragma unroll
            for (int i = 0; i < 4; i++) a[i] = As[k][ty * 4 + i];
            #pragma unroll
            for (int j = 0; j < 4; j++) b[j] = Ws[k][tx * 4 + j];
            #pragma unroll
            for (int i = 0; i < 4; i++)
                #pragma unroll
                for (int j = 0; j < 4; j++)
                    acc[i][j] += a[i] * b[j];
        }
    }
    #pragma unroll
    for (int i = 0; i < 4; i++)
        #pragma unroll
        for (int j = 0; j < 4; j++)
            C[(size_t)(bm + ty * 4 + i) * NN + bn + tx * 4 + j] =
                acc[i][j] + bias[bn + tx * 4 + j];
}

extern "C" void kernel_launch(void* const* d_in, const int* in_sizes, int n_in,
                              void* d_out, int out_size, void* d_ws, size_t ws_size,
                              hipStream_t stream) {
    const float* x    = (const float*)d_in[0];
    const float* W    = (const float*)d_in[1];
    const float* bias = (const float*)d_in[2];
    float* out = (float*)d_out;

    const size_t need_wt   = (size_t)NN * KK * 2;              // 32 MiB
    const size_t need_full = need_wt + (size_t)MM * KK * 2;    // 96 MiB

    if (ws_size >= need_full) {
        // fast path: one fused prep (W transpose+cast || x cast), then GEMM
        unsigned short* wt = (unsigned short*)d_ws;
        unsigned short* xb = wt + (size_t)NN * KK;
        const int xblks = (int)((size_t)MM * KK / 2048);       // 16384
        prep<<<WTBLKS + xblks, 256, 0, stream>>>(x, W, xb, wt);
        gemm_bt<false><<<dim3(NN / BN, MM / BM), 256, 0, stream>>>(xb, wt, bias, out);
    } else if (ws_size >= need_wt) {
        // wt-only path: W transposed+cast in ws; x converted during staging
        unsigned short* wt = (unsigned short*)d_ws;
        prep<<<WTBLKS, 256, 0, stream>>>(x, W, nullptr, wt);
        gemm_bt<true><<<dim3(NN / BN, MM / BM), 256, 0, stream>>>(x, wt, bias, out);
    } else {
        // insurance: fp32 vector GEMM, no workspace
        gemm_f32<<<dim3(NN / 64, MM / 64), 256, 0, stream>>>(x, W, bias, out);
    }
}